// Round 14
// baseline (379.458 us; speedup 1.0000x reference)
//
#include <hip/hip_runtime.h>
#include <hip/hip_bf16.h>

#define B_ 4
#define N_ 8192
#define KNN 16
#define BN_ (B_*N_)      // 32768
#define NPOS (BN_*KNN)   // 524288

typedef __attribute__((ext_vector_type(8))) short bf16x8;
typedef __attribute__((ext_vector_type(4))) float f32x4;

static __device__ __forceinline__ unsigned short f2bf(float f) {
  union { float f; unsigned u; } v; v.f = f;
  unsigned r = v.u + 0x7fff + ((v.u >> 16) & 1);
  return (unsigned short)(r >> 16);
}
static __device__ __forceinline__ float lk(float x) { return x >= 0.f ? x : 0.2f*x; }
static __device__ __forceinline__ unsigned pk2(float a, float b) {
  return (unsigned)f2bf(a) | ((unsigned)f2bf(b) << 16);
}

// ---------------- prep: pts4 = (x,y,z,|p|^2) ----------------
__global__ void k_prep(const float* __restrict__ xyz, float4* __restrict__ pts4) {
  int i = blockIdx.x * 256 + threadIdx.x;
  if (i >= BN_) return;
  int b = i >> 13, n = i & (N_-1);
  const float* p = xyz + b*3*N_;
  float x = p[n], y = p[N_+n], z = p[2*N_+n];
  float xx = fmaf(z, z, fmaf(y, y, x*x));
  pts4[i] = make_float4(x, y, z, xx);
}

// ------- convert ALL weights to bf16, PRE-SWIZZLED LDS images -------
__global__ void k_wcvt(const float* __restrict__ w_sc, const float* __restrict__ w_a,
                       const float* __restrict__ w_b, const float* __restrict__ w_c,
                       const float* __restrict__ p1a, const float* __restrict__ p1sc,
                       const float* __restrict__ p1b, const float* __restrict__ p1c,
                       unsigned short* __restrict__ out) {
  int i = blockIdx.x*256 + threadIdx.x;
  if (i >= 61440) return;
  if (i < 49152) {
    int x = i*2;                            // byte offset in p2 image
    const float* w; int base, K2;
    if (x < 32768)      { w = w_sc; base = 0;     K2 = 256; }
    else if (x < 49152) { w = w_a;  base = 32768; K2 = 256; }
    else if (x < 65536) { w = w_b;  base = 49152; K2 = 128; }
    else                { w = w_c;  base = 65536; K2 = 256; }
    int off = x - base;
    int row = off / K2;
    int colb = (off & (K2-1)) ^ ((row & 7) << 4);
    int k = colb >> 1;
    out[i] = f2bf(w[row*(K2 >> 1) + k]);
  } else {
    int e = i - 49152;                      // 0..12287
    float val; int byteoff;
    if (e < 2048) {               // Wa 64x32 (64B rows)
      int row = e >> 5, k = e & 31;
      val = (k < 10) ? p1a[row*10 + k] : 0.f;
      byteoff = row*64 + ((2*k) ^ ((row & 3) << 4));
    } else if (e < 4096) {        // Wsc 64x32
      int le = e - 2048, row = le >> 5, k = le & 31;
      val = (k < 10) ? p1sc[row*10 + k] : 0.f;
      byteoff = 4096 + row*64 + ((2*k) ^ ((row & 3) << 4));
    } else if (e < 8192) {        // Wb 64x64 (128B rows)
      int le = e - 4096, row = le >> 6, k = le & 63;
      val = p1b[row*64 + k];
      byteoff = 8192 + row*128 + ((2*k) ^ ((row & 7) << 4));
    } else {                      // Wc 64x64
      int le = e - 8192, row = le >> 6, k = le & 63;
      val = p1c[row*64 + k];
      byteoff = 16384 + row*128 + ((2*k) ^ ((row & 7) << 4));
    }
    out[49152 + (byteoff >> 1)] = f2bf(val);
  }
}

// ---------------- KNN (round-7 proven: U=4 batched scan + ballot-append) ----------------
static __device__ __forceinline__ unsigned long long bitonic64(
    unsigned long long key, int lane) {
  #pragma unroll
  for (int size = 2; size <= 64; size <<= 1) {
    #pragma unroll
    for (int stride = size >> 1; stride >= 1; stride >>= 1) {
      unsigned long long ok = __shfl_xor((long long)key, stride);
      bool up = ((lane & size) == 0);
      bool keepmin = (((lane & stride) == 0) == up);
      bool oless = ok < key;
      if (oless == keepmin) key = ok;
    }
  }
  return key;
}

template<int U>
static __device__ __forceinline__ void scan_groups(
    const float4* __restrict__ cand, int itbase, int ch,
    float4 me, int lane,
    unsigned long long* __restrict__ bw,
    unsigned long long& topk, float& rhs, int& cnt) {
  float s[U]; int cid[U];
  #pragma unroll
  for (int u = 0; u < U; ++u) {
    int ci = (itbase + u)*64 + lane;
    float4 c = cand[ci];
    float dot = fmaf(me.z, c.z, fmaf(me.y, c.y, me.x*c.x));
    s[u] = fmaf(-2.0f, dot, c.w);          // d2 = me.w + s
    cid[u] = ch*2048 + ci;
  }
  #pragma unroll
  for (int u = 0; u < U; ++u) {
    unsigned long long m = __ballot(s[u] < rhs);
    if (m) {
      int prefix = __builtin_amdgcn_mbcnt_hi((unsigned)(m >> 32),
                    __builtin_amdgcn_mbcnt_lo((unsigned)m, 0));
      if (s[u] < rhs) {
        float d2 = me.w + s[u];
        bw[cnt + prefix] =
          ((unsigned long long)__float_as_uint(d2) << 32) | (unsigned)cid[u];
      }
      cnt += __popcll(m);
      if (cnt >= 48) {
        int base = 0;
        while (cnt > 0) {
          int c2 = cnt > 48 ? 48 : cnt;
          unsigned long long e = (lane < 16) ? topk
            : ((lane - 16) < c2 ? bw[base + lane - 16] : ~0ull);
          topk = bitonic64(e, lane);
          base += c2; cnt -= c2;
        }
        unsigned long long k15 = __shfl((long long)topk, 15);
        rhs = __uint_as_float((unsigned)(k15 >> 32)) - me.w;
      }
    }
  }
}

__global__ __launch_bounds__(512) void k_knn(const float4* __restrict__ pts4,
                                             int* __restrict__ knn) {
  __shared__ float4 cand[2048];
  __shared__ unsigned long long buf[8][112];
  const int lane = threadIdx.x & 63;
  const int wv   = threadIdx.x >> 6;
  const int q = blockIdx.x * 8 + wv;
  const int b = q >> 13;
  const int n = q & (N_-1);
  const float4* __restrict__ P = pts4 + (b << 13);
  float4 me = P[n];

  unsigned long long topk = ~0ull;
  float rhs = __builtin_inff();
  int cnt = 0;
  unsigned long long* __restrict__ bw = buf[wv];

  for (int ch = 0; ch < 4; ++ch) {
    __syncthreads();
    #pragma unroll
    for (int t = 0; t < 4; ++t)
      cand[t*512 + threadIdx.x] = P[ch*2048 + t*512 + threadIdx.x];
    __syncthreads();

    if (ch == 0) {
      float4 c = cand[lane];
      float dot = fmaf(me.z, c.z, fmaf(me.y, c.y, me.x*c.x));
      float d2 = (me.w + c.w) - 2.0f*dot;
      unsigned long long key =
        ((unsigned long long)__float_as_uint(d2) << 32) | (unsigned)lane;
      topk = bitonic64(key, lane);
      unsigned long long k15 = __shfl((long long)topk, 15);
      rhs = __uint_as_float((unsigned)(k15 >> 32)) - me.w;
      scan_groups<3>(cand, 1, 0, me, lane, bw, topk, rhs, cnt);
      #pragma unroll 1
      for (int it = 4; it < 32; it += 4)
        scan_groups<4>(cand, it, 0, me, lane, bw, topk, rhs, cnt);
    } else {
      #pragma unroll 1
      for (int it = 0; it < 32; it += 4)
        scan_groups<4>(cand, it, ch, me, lane, bw, topk, rhs, cnt);
    }
  }
  {
    int base = 0;
    while (cnt > 0) {
      int c2 = cnt > 48 ? 48 : cnt;
      unsigned long long e = (lane < 16) ? topk
        : ((lane - 16) < c2 ? bw[base + lane - 16] : ~0ull);
      topk = bitonic64(e, lane);
      base += c2; cnt -= c2;
    }
  }
  if (lane < 16) knn[(q << 4) + lane] = (int)(unsigned)(topk & 0xffffffffu);
}

// ================ FUSED phase-1 + phase-2 (no X/XM global round-trip) ================
// 256 blocks x 512 thr (8 waves); block handles 128 bn = 8 tiles of 16 bn.
// Wave owns bn pair {bn0+2wv, bn0+2wv+1} as 2 col-tiles of 16 (cols = 16 neighbors).
// Per tile: features in-register -> p1 SC/A/B/C (LDS Ws1) -> p1 acc -> wave-local
// LDS X-rows + XM (shfl-reduce) -> p2 bx fragments -> p2 SC/A/B/C (LDS Ws2)
// -> max-over-k -> coalesced out store. outT aliases Hr (barrier-protected).
__global__ __launch_bounds__(512, 2) void k_p12(
    const float4* __restrict__ pts4, const int* __restrict__ knn,
    const unsigned short* __restrict__ wbf,
    const float* __restrict__ a_b1, const float* __restrict__ b_b1,
    const float* __restrict__ c_b1, const float* __restrict__ sc_b1,
    const float* __restrict__ sc_b2, const float* __restrict__ a_b2,
    const float* __restrict__ b_b2, const float* __restrict__ c_b2,
    float* __restrict__ out) {
  __shared__ __align__(16) unsigned short Ws1[12288];   // 24 KB p1 weights
  __shared__ __align__(16) unsigned short Ws2[49152];   // 96 KB p2 weights
  __shared__ __align__(16) unsigned short Hr[8][2304];  // 4 KB H + 256B XM per wave
  const int tid = threadIdx.x;
  const int lane = tid & 63, wv = tid >> 6;
  const int colr = lane & 15, kq = lane >> 4;

  // stage weights ONCE
  #pragma unroll
  for (int j = 0; j < 3; ++j)
    ((uint4*)Ws1)[j*512 + tid] = ((const uint4*)(wbf + 49152))[j*512 + tid];
  #pragma unroll
  for (int it = 0; it < 12; ++it)
    ((uint4*)Ws2)[it*512 + tid] = ((const uint4*)wbf)[it*512 + tid];

  const char* WS = (const char*)Ws1;
  const char* WSC = (const char*)Ws2;              // 128x128, K2=256
  const char* WA  = (const char*)(Ws2 + 16384);    // 64x128,  K2=256
  const char* WB  = (const char*)(Ws2 + 24576);    // 128x64,  K2=128
  const char* WC  = (const char*)(Ws2 + 32768);    // 128x128, K2=256
  char* H = (char*)Hr[wv];
  float (*outT)[16] = (float(*)[16])(&Hr[0][0]);   // 8 KB alias, barrier-protected

#define WF(base, row, K2, ksbyte) \
  (*(const bf16x8*)((base) + (row)*(K2) + ((((ksbyte) + kq*16)) ^ (((row)&7)<<4))))

  __syncthreads();   // weights staged

  for (int t = 0; t < 8; ++t) {
    const int bn0 = blockIdx.x*128 + t*16;

    // ---- gather + features in registers (redundant across kq quads) ----
    unsigned short fb0[10], fb1[10];
    #pragma unroll
    for (int ct = 0; ct < 2; ++ct) {
      int bn = bn0 + wv*2 + ct;
      int b = bn >> 13;
      float4 cp = pts4[bn];
      int nid = knn[bn*16 + colr];
      float4 np = pts4[(b << 13) + nid];
      float rx = np.x - cp.x, ry = np.y - cp.y, rz = np.z - cp.z;
      float dist = sqrtf(fmaf(rz, rz, fmaf(ry, ry, rx*rx)) + 1e-12f);
      unsigned short* fb = ct ? fb1 : fb0;
      fb[0]=f2bf(cp.x); fb[1]=f2bf(cp.y); fb[2]=f2bf(cp.z);
      fb[3]=f2bf(np.x); fb[4]=f2bf(np.y); fb[5]=f2bf(np.z);
      fb[6]=f2bf(rx);   fb[7]=f2bf(ry);   fb[8]=f2bf(rz);   fb[9]=f2bf(dist);
    }
    bf16x8 bfr[2];
    #pragma unroll
    for (int ct = 0; ct < 2; ++ct) {
      const unsigned short* fb = ct ? fb1 : fb0;
      #pragma unroll
      for (int j = 0; j < 8; ++j) {
        unsigned short v1 = (j < 2) ? fb[8+j] : (unsigned short)0;
        unsigned short e = (kq == 0) ? fb[j] : ((kq == 1) ? v1 : (unsigned short)0);
        bfr[ct][j] = (short)e;
      }
    }

    // ---- p1 SC GEMM (acc init c_b1 + sc_b1) ----
    f32x4 acc1[4][2];
    #pragma unroll
    for (int mt = 0; mt < 4; ++mt) {
      int r0 = mt*16 + kq*4;
      #pragma unroll
      for (int r = 0; r < 4; ++r) {
        float bia = c_b1[r0+r] + sc_b1[r0+r];
        acc1[mt][0][r] = bia; acc1[mt][1][r] = bia;
      }
    }
    #pragma unroll
    for (int mt = 0; mt < 4; ++mt) {
      int row = mt*16 + colr;
      bf16x8 w = *(const bf16x8*)(WS + 4096 + row*64 + ((kq*16) ^ ((row&3)<<4)));
      acc1[mt][0] = __builtin_amdgcn_mfma_f32_16x16x32_bf16(w, bfr[0], acc1[mt][0], 0, 0, 0);
      acc1[mt][1] = __builtin_amdgcn_mfma_f32_16x16x32_bf16(w, bfr[1], acc1[mt][1], 0, 0, 0);
    }

    // ---- p1 A GEMM ----
    f32x4 ha[4][2];
    #pragma unroll
    for (int mt = 0; mt < 4; ++mt) {
      int r0 = mt*16 + kq*4;
      #pragma unroll
      for (int r = 0; r < 4; ++r) { ha[mt][0][r] = a_b1[r0+r]; ha[mt][1][r] = a_b1[r0+r]; }
    }
    #pragma unroll
    for (int mt = 0; mt < 4; ++mt) {
      int row = mt*16 + colr;
      bf16x8 w = *(const bf16x8*)(WS + row*64 + ((kq*16) ^ ((row&3)<<4)));
      ha[mt][0] = __builtin_amdgcn_mfma_f32_16x16x32_bf16(w, bfr[0], ha[mt][0], 0, 0, 0);
      ha[mt][1] = __builtin_amdgcn_mfma_f32_16x16x32_bf16(w, bfr[1], ha[mt][1], 0, 0, 0);
    }

    // ---- p1 leaky + h1 -> H ----
    #pragma unroll
    for (int mt = 0; mt < 4; ++mt) {
      int ch2 = (mt*16 + kq*4) * 2;
      #pragma unroll
      for (int ct = 0; ct < 2; ++ct) {
        int posl = ct*16 + colr;
        uint2 u;
        u.x = pk2(lk(ha[mt][ct][0]), lk(ha[mt][ct][1]));
        u.y = pk2(lk(ha[mt][ct][2]), lk(ha[mt][ct][3]));
        *(uint2*)(H + posl*128 + (ch2 ^ ((posl&7)<<4))) = u;
      }
    }
    bf16x8 bh1[2][2];
    #pragma unroll
    for (int ct = 0; ct < 2; ++ct) {
      int posl = ct*16 + colr;
      #pragma unroll
      for (int k2 = 0; k2 < 2; ++k2)
        bh1[ct][k2] = *(const bf16x8*)(H + posl*128 + ((k2*64 + kq*16) ^ ((posl&7)<<4)));
    }

    // ---- p1 B pairs interleaved with C k-slices ----
    #pragma unroll
    for (int jj = 0; jj < 2; ++jj) {
      f32x4 h2[2][2];
      #pragma unroll
      for (int mtp = 0; mtp < 2; ++mtp) {
        int r0 = (jj*2 + mtp)*16 + kq*4;
        #pragma unroll
        for (int r = 0; r < 4; ++r) { h2[mtp][0][r] = b_b1[r0+r]; h2[mtp][1][r] = b_b1[r0+r]; }
      }
      #pragma unroll
      for (int mtp = 0; mtp < 2; ++mtp) {
        int row = (jj*2 + mtp)*16 + colr;
        #pragma unroll
        for (int k2 = 0; k2 < 2; ++k2) {
          bf16x8 w = *(const bf16x8*)(WS + 8192 + row*128 + ((k2*64 + kq*16) ^ ((row&7)<<4)));
          h2[mtp][0] = __builtin_amdgcn_mfma_f32_16x16x32_bf16(w, bh1[0][k2], h2[mtp][0], 0, 0, 0);
          h2[mtp][1] = __builtin_amdgcn_mfma_f32_16x16x32_bf16(w, bh1[1][k2], h2[mtp][1], 0, 0, 0);
        }
      }
      #pragma unroll
      for (int mtp = 0; mtp < 2; ++mtp) {
        int ch2 = ((jj*2 + mtp)*16 + kq*4) * 2;
        #pragma unroll
        for (int ct = 0; ct < 2; ++ct) {
          int posl = ct*16 + colr;
          uint2 u;
          u.x = pk2(lk(h2[mtp][ct][0]), lk(h2[mtp][ct][1]));
          u.y = pk2(lk(h2[mtp][ct][2]), lk(h2[mtp][ct][3]));
          *(uint2*)(H + posl*128 + (ch2 ^ ((posl&7)<<4))) = u;
        }
      }
      bf16x8 b2[2];
      #pragma unroll
      for (int ct = 0; ct < 2; ++ct) {
        int posl = ct*16 + colr;
        b2[ct] = *(const bf16x8*)(H + posl*128 + ((jj*64 + kq*16) ^ ((posl&7)<<4)));
      }
      #pragma unroll
      for (int mt = 0; mt < 4; ++mt) {
        int row = mt*16 + colr;
        bf16x8 w = *(const bf16x8*)(WS + 16384 + row*128 + ((jj*64 + kq*16) ^ ((row&7)<<4)));
        acc1[mt][0] = __builtin_amdgcn_mfma_f32_16x16x32_bf16(w, b2[0], acc1[mt][0], 0, 0, 0);
        acc1[mt][1] = __builtin_amdgcn_mfma_f32_16x16x32_bf16(w, b2[1], acc1[mt][1], 0, 0, 0);
      }
    }

    // ---- p1 acc -> LDS X-rows (swizzled) + XM (shfl max over 16 cols) ----
    #pragma unroll
    for (int ct = 0; ct < 2; ++ct) {
      int posl = ct*16 + colr;
      #pragma unroll
      for (int mt = 0; mt < 4; ++mt) {
        int ch0 = mt*16 + kq*4;
        uint2 u;
        u.x = pk2(acc1[mt][ct][0], acc1[mt][ct][1]);
        u.y = pk2(acc1[mt][ct][2], acc1[mt][ct][3]);
        *(uint2*)(H + ((posl*128 + ch0*2) ^ ((posl&7)<<4))) = u;
        float m[4];
        #pragma unroll
        for (int r = 0; r < 4; ++r) {
          float v = acc1[mt][ct][r];
          v = fmaxf(v, __shfl_xor(v, 1));
          v = fmaxf(v, __shfl_xor(v, 2));
          v = fmaxf(v, __shfl_xor(v, 4));
          v = fmaxf(v, __shfl_xor(v, 8));
          m[r] = v;
        }
        if (colr == 0) {
          uint2 um; um.x = pk2(m[0], m[1]); um.y = pk2(m[2], m[3]);
          *(uint2*)(H + 4096 + ct*128 + ch0*2) = um;
        }
      }
    }

    // ---- p2 bx fragments from LDS ----
    bf16x8 bx[2][4];
    #pragma unroll
    for (int ct = 0; ct < 2; ++ct) {
      int posl = ct*16 + colr;
      bx[ct][0] = *(const bf16x8*)(H + ((posl*128 + kq*16) ^ ((posl&7)<<4)));
      bx[ct][1] = *(const bf16x8*)(H + ((posl*128 + 64 + kq*16) ^ ((posl&7)<<4)));
      bx[ct][2] = *(const bf16x8*)(H + 4096 + ct*128 + kq*16);
      bx[ct][3] = *(const bf16x8*)(H + 4096 + ct*128 + 64 + kq*16);
    }

    // ---- p2 SC GEMM (acc init c_b2 + sc_b2) ----
    f32x4 acc[8][2];
    #pragma unroll
    for (int mt = 0; mt < 8; ++mt) {
      int r0 = mt*16 + kq*4;
      #pragma unroll
      for (int r = 0; r < 4; ++r) {
        float bia = c_b2[r0+r] + sc_b2[r0+r];
        acc[mt][0][r] = bia; acc[mt][1][r] = bia;
      }
    }
    #pragma unroll
    for (int mt = 0; mt < 8; ++mt) {
      int row = mt*16 + colr;
      #pragma unroll
      for (int ks = 0; ks < 4; ++ks) {
        bf16x8 w = WF(WSC, row, 256, ks*64);
        acc[mt][0] = __builtin_amdgcn_mfma_f32_16x16x32_bf16(w, bx[0][ks], acc[mt][0], 0, 0, 0);
        acc[mt][1] = __builtin_amdgcn_mfma_f32_16x16x32_bf16(w, bx[1][ks], acc[mt][1], 0, 0, 0);
      }
    }

    // ---- p2 A GEMM ----
    f32x4 ha2[4][2];
    #pragma unroll
    for (int mt = 0; mt < 4; ++mt) {
      int r0 = mt*16 + kq*4;
      #pragma unroll
      for (int r = 0; r < 4; ++r) { ha2[mt][0][r] = a_b2[r0+r]; ha2[mt][1][r] = a_b2[r0+r]; }
    }
    #pragma unroll
    for (int mt = 0; mt < 4; ++mt) {
      int row = mt*16 + colr;
      #pragma unroll
      for (int ks = 0; ks < 4; ++ks) {
        bf16x8 w = WF(WA, row, 256, ks*64);
        ha2[mt][0] = __builtin_amdgcn_mfma_f32_16x16x32_bf16(w, bx[0][ks], ha2[mt][0], 0, 0, 0);
        ha2[mt][1] = __builtin_amdgcn_mfma_f32_16x16x32_bf16(w, bx[1][ks], ha2[mt][1], 0, 0, 0);
      }
    }

    // ---- p2 leaky + h1 -> H (overwrites X rows; bx already in registers) ----
    #pragma unroll
    for (int mt = 0; mt < 4; ++mt) {
      int ch2 = (mt*16 + kq*4) * 2;
      #pragma unroll
      for (int ct = 0; ct < 2; ++ct) {
        int posl = ct*16 + colr;
        uint2 u;
        u.x = pk2(lk(ha2[mt][ct][0]), lk(ha2[mt][ct][1]));
        u.y = pk2(lk(ha2[mt][ct][2]), lk(ha2[mt][ct][3]));
        *(uint2*)(H + posl*128 + (ch2 ^ ((posl&7)<<4))) = u;
      }
    }
    bf16x8 bh[2][2];
    #pragma unroll
    for (int ct = 0; ct < 2; ++ct) {
      int posl = ct*16 + colr;
      #pragma unroll
      for (int k2 = 0; k2 < 2; ++k2)
        bh[ct][k2] = *(const bf16x8*)(H + posl*128 + ((k2*64 + kq*16) ^ ((posl&7)<<4)));
    }

    // ---- p2 B pairs interleaved with C k-slices ----
    #pragma unroll
    for (int j = 0; j < 4; ++j) {
      f32x4 h2[2][2];
      #pragma unroll
      for (int mtp = 0; mtp < 2; ++mtp) {
        int r0 = (2*j + mtp)*16 + kq*4;
        #pragma unroll
        for (int r = 0; r < 4; ++r) { h2[mtp][0][r] = b_b2[r0+r]; h2[mtp][1][r] = b_b2[r0+r]; }
      }
      #pragma unroll
      for (int mtp = 0; mtp < 2; ++mtp) {
        int row = (2*j + mtp)*16 + colr;
        #pragma unroll
        for (int k2 = 0; k2 < 2; ++k2) {
          bf16x8 w = WF(WB, row, 128, k2*64);
          h2[mtp][0] = __builtin_amdgcn_mfma_f32_16x16x32_bf16(w, bh[0][k2], h2[mtp][0], 0, 0, 0);
          h2[mtp][1] = __builtin_amdgcn_mfma_f32_16x16x32_bf16(w, bh[1][k2], h2[mtp][1], 0, 0, 0);
        }
      }
      char* PB = H + (j & 1)*2048;
      #pragma unroll
      for (int mtp = 0; mtp < 2; ++mtp) {
        int chp2 = (mtp*16 + kq*4) * 2;
        #pragma unroll
        for (int ct = 0; ct < 2; ++ct) {
          int posl = ct*16 + colr;
          uint2 u;
          u.x = pk2(lk(h2[mtp][ct][0]), lk(h2[mtp][ct][1]));
          u.y = pk2(lk(h2[mtp][ct][2]), lk(h2[mtp][ct][3]));
          *(uint2*)(PB + posl*64 + (chp2 ^ ((posl&3)<<4))) = u;
        }
      }
      bf16x8 b2[2];
      #pragma unroll
      for (int ct = 0; ct < 2; ++ct) {
        int posl = ct*16 + colr;
        b2[ct] = *(const bf16x8*)(PB + posl*64 + ((kq*16) ^ ((posl&3)<<4)));
      }
      #pragma unroll
      for (int mt = 0; mt < 8; ++mt) {
        int row = mt*16 + colr;
        bf16x8 w = WF(WC, row, 256, j*64);
        acc[mt][0] = __builtin_amdgcn_mfma_f32_16x16x32_bf16(w, b2[0], acc[mt][0], 0, 0, 0);
        acc[mt][1] = __builtin_amdgcn_mfma_f32_16x16x32_bf16(w, b2[1], acc[mt][1], 0, 0, 0);
      }
    }

    // ---- epilogue: max over k -> outT (aliases Hr, barrier-protected) ----
    __syncthreads();   // all waves done with Hr this tile
    #pragma unroll
    for (int mt = 0; mt < 8; ++mt) {
      #pragma unroll
      for (int ct = 0; ct < 2; ++ct) {
        #pragma unroll
        for (int r = 0; r < 4; ++r) {
          float v = acc[mt][ct][r];
          v = fmaxf(v, __shfl_xor(v, 1));
          v = fmaxf(v, __shfl_xor(v, 2));
          v = fmaxf(v, __shfl_xor(v, 4));
          v = fmaxf(v, __shfl_xor(v, 8));
          if (colr == 0) outT[mt*16 + kq*4 + r][wv*2 + ct] = v;
        }
      }
    }
    __syncthreads();
    {
      int ch = tid >> 2, p = tid & 3;
      int b = bn0 >> 13, n0 = bn0 & (N_-1);
      float4 v4 = *(const float4*)&outT[ch][p*4];
      *(float4*)(out + ((size_t)b*128 + ch)*N_ + n0 + p*4) = v4;
    }
    __syncthreads();   // outT readers done before next tile's Hr writes
  }
#undef WF
}

extern "C" void kernel_launch(void* const* d_in, const int* in_sizes, int n_in,
                              void* d_out, int out_size, void* d_ws, size_t ws_size,
                              hipStream_t stream) {
  const float* xyz     = (const float*)d_in[0];
  const float* p1_sc_w = (const float*)d_in[1];
  const float* p1_sc_b = (const float*)d_in[2];
  const float* p1_a_w  = (const float*)d_in[3];
  const float* p1_a_b  = (const float*)d_in[4];
  const float* p1_b_w  = (const float*)d_in[5];
  const float* p1_b_b  = (const float*)d_in[6];
  const float* p1_c_w  = (const float*)d_in[7];
  const float* p1_c_b  = (const float*)d_in[8];
  const float* p2_sc_w = (const float*)d_in[9];
  const float* p2_sc_b = (const float*)d_in[10];
  const float* p2_a_w  = (const float*)d_in[11];
  const float* p2_a_b  = (const float*)d_in[12];
  const float* p2_b_w  = (const float*)d_in[13];
  const float* p2_b_b  = (const float*)d_in[14];
  const float* p2_c_w  = (const float*)d_in[15];
  const float* p2_c_b  = (const float*)d_in[16];

  if (ws_size < 75497472u) return;
  char* ws = (char*)d_ws;
  float4* pts4        = (float4*)(ws);
  unsigned short* wbf = (unsigned short*)(ws + 524288);
  int* knn            = (int*)(ws + 655360);
  float* out = (float*)d_out;

  k_prep<<<dim3(BN_/256), dim3(256), 0, stream>>>(xyz, pts4);
  k_wcvt<<<dim3(240), dim3(256), 0, stream>>>(p2_sc_w, p2_a_w, p2_b_w, p2_c_w,
      p1_a_w, p1_sc_w, p1_b_w, p1_c_w, wbf);
  k_knn<<<dim3(BN_/8), dim3(512), 0, stream>>>(pts4, knn);
  k_p12<<<dim3(256), dim3(512), 0, stream>>>(pts4, knn, wbf,
      p1_a_b, p1_b_b, p1_c_b, p1_sc_b,
      p2_sc_b, p2_a_b, p2_b_b, p2_c_b, out);
}